// Round 8
// baseline (1434.643 us; speedup 1.0000x reference)
//
#include <hip/hip_runtime.h>
#include <hip/hip_bf16.h>

// Problem constants
#define NOBJ   2048
#define NREL   32768
#define NCLS   151      // IMG_NUM_OBJ
#define NCLSP  152      // padded
#define NPRED  51
#define EMB    512
#define MIDW   512
#define FINALW 1024
#define NG     2

// ---------------- workspace layout (bytes) ----------------
constexpr size_t align_up(size_t x) { return (x + 255) & ~size_t(255); }
constexpr size_t OFF_SCALES = 0;                                         // 6 f
constexpr size_t OFF_CNT    = align_up(OFF_SCALES + 6 * 4);              // 152 i
constexpr size_t OFF_START  = align_up(OFF_CNT + NCLSP * 4);             // 152 i
constexpr size_t OFF_ORDER  = align_up(OFF_START + NCLSP * 4);           // 2048 i
constexpr size_t OFF_INVS   = align_up(OFF_ORDER + NOBJ * 4);            // 2048 f
constexpr size_t OFF_ATAB   = align_up(OFF_INVS + NOBJ * 4);             // [2][3][152][512] f
constexpr size_t OFF_BTAB   = align_up(OFF_ATAB + size_t(NG)*3*NCLSP*MIDW*4); // [2][152][512] f
constexpr size_t OFF_GT     = align_up(OFF_BTAB + size_t(NG)*NCLSP*MIDW*4);   // [152][32768] f
constexpr size_t OFF_M      = align_up(OFF_GT + size_t(NCLSP)*NREL*4);   // [2][152][512] f
constexpr size_t OFF_H      = align_up(OFF_M + size_t(NG)*NCLSP*MIDW*4); // [2][512]
constexpr size_t OFF_AH     = align_up(OFF_H + NG*MIDW*4);               // [2][512]
constexpr size_t OFF_C1     = align_up(OFF_AH + NG*MIDW*4);              // [512]
constexpr size_t OFF_SG     = align_up(OFF_C1 + MIDW*4);                 // [512]
constexpr size_t OFF_O1     = align_up(OFF_SG + MIDW*4);                 // [512]
constexpr size_t OFF_MPART  = align_up(OFF_O1 + MIDW*4);
constexpr size_t MPART_UNIT = size_t(NG)*NCLSP*MIDW*4;                   // per r-chunk slice

// ---------------- kernels ----------------

// 6 blocks: weight-norm scalar scales s = g / ||V||_F for lin_v[0..1], lin_q[0..1], lin_a[0..1]
__global__ void k_scales(const float* lin_v_v, const float* lin_v_g,
                         const float* lin_q_v, const float* lin_q_g,
                         const float* lin_a_v, const float* lin_a_g,
                         float* scales) {
    int b = blockIdx.x;
    const float* src; size_t n; float gval;
    if (b < 2)      { src = lin_v_v + size_t(b) * MIDW * 3 * EMB; n = size_t(MIDW) * 3 * EMB; gval = lin_v_g[b]; }
    else if (b < 4) { src = lin_q_v + size_t(b - 2) * MIDW * EMB; n = size_t(MIDW) * EMB;     gval = lin_q_g[b - 2]; }
    else            { src = lin_a_v + size_t(b - 4) * MIDW * MIDW; n = size_t(MIDW) * MIDW;   gval = lin_a_g[b - 4]; }
    float ss = 0.f;
    const float4* s4 = (const float4*)src;
    for (size_t i = threadIdx.x; i < n / 4; i += blockDim.x) {
        float4 v = s4[i];
        ss += v.x * v.x + v.y * v.y + v.z * v.z + v.w * v.w;
    }
    for (int off = 32; off; off >>= 1) ss += __shfl_down(ss, off);
    __shared__ float red[4];
    int lane = threadIdx.x & 63, w = threadIdx.x >> 6;
    if (lane == 0) red[w] = ss;
    __syncthreads();
    if (threadIdx.x == 0) {
        float t = red[0] + red[1] + red[2] + red[3];
        scales[b] = gval / sqrtf(t);
    }
}

// 1 block: histogram of entities + class start offsets + object order bucketed by class
__global__ void k_bucket(const int* entities, int* cnt, int* start, int* order) {
    __shared__ int h[NCLS];
    __shared__ int st[NCLSP];
    for (int i = threadIdx.x; i < NCLS; i += blockDim.x) h[i] = 0;
    __syncthreads();
    for (int o = threadIdx.x; o < NOBJ; o += blockDim.x) atomicAdd(&h[entities[o]], 1);
    __syncthreads();
    if (threadIdx.x == 0) {
        int acc = 0;
        for (int i = 0; i < NCLS; i++) { st[i] = acc; acc += h[i]; }
        st[NCLS] = acc;
    }
    __syncthreads();
    for (int i = threadIdx.x; i < NCLS; i += blockDim.x) cnt[i] = h[i];
    for (int i = threadIdx.x; i < NCLSP; i += blockDim.x) start[i] = (i <= NCLS) ? st[i] : st[NCLS];
    __syncthreads();
    for (int i = threadIdx.x; i < NCLS; i += blockDim.x) h[i] = st[i];  // reuse as cursors
    __syncthreads();
    for (int o = threadIdx.x; o < NOBJ; o += blockDim.x) {
        int c = entities[o];
        int p = atomicAdd(&h[c], 1);
        order[p] = o;
    }
}

// 128 blocks: A tables (head/tail/pred vs lin_v_v slices) and B tables (obj vs lin_q_v), wn-scaled
__global__ __launch_bounds__(256) void k_tables(
        const float* obj_tab, const float* head_tab, const float* tail_tab,
        const float* pred_tab, const float* lin_v_v, const float* lin_q_v,
        const float* scales, float* Atab, float* Btab) {
    int jb = blockIdx.x;
    int g = jb >> 6;
    int r = jb & 63;
    int tbl, ib;
    if (r < 19)      { tbl = 0; ib = r; }
    else if (r < 38) { tbl = 1; ib = r - 19; }
    else if (r < 45) { tbl = 2; ib = r - 38; }
    else             { tbl = 3; ib = r - 45; }
    int nrows = (tbl == 2) ? NPRED : NCLS;
    int i0 = ib * 8;
    int nr = min(8, nrows - i0);
    const float* xsrc = (tbl == 0) ? head_tab : (tbl == 1) ? tail_tab : (tbl == 2) ? pred_tab : obj_tab;
    const float* W; int wstride, woff; float s;
    if (tbl < 3) { W = lin_v_v + size_t(g) * MIDW * 3 * EMB; wstride = 3 * EMB; woff = tbl * EMB; s = scales[g]; }
    else         { W = lin_q_v + size_t(g) * MIDW * EMB;     wstride = EMB;     woff = 0;         s = scales[2 + g]; }

    __shared__ float xl[8][EMB];
    for (int idx = threadIdx.x; idx < 8 * 128; idx += 256) {
        int ii = idx >> 7, e4 = idx & 127;
        float4 v = (ii < nr) ? ((const float4*)(xsrc + size_t(i0 + ii) * EMB))[e4]
                             : make_float4(0.f, 0.f, 0.f, 0.f);
        ((float4*)&xl[ii][0])[e4] = v;
    }
    __syncthreads();

    int m1 = threadIdx.x, m2 = threadIdx.x + 256;
    float acc1[8] = {0,0,0,0,0,0,0,0};
    float acc2[8] = {0,0,0,0,0,0,0,0};
    const float4* w1p = (const float4*)(W + size_t(m1) * wstride + woff);
    const float4* w2p = (const float4*)(W + size_t(m2) * wstride + woff);
    for (int e4 = 0; e4 < 128; e4++) {
        float4 w1 = w1p[e4];
        float4 w2 = w2p[e4];
#pragma unroll
        for (int ii = 0; ii < 8; ii++) {
            float4 x = ((const float4*)&xl[ii][0])[e4];
            acc1[ii] += w1.x * x.x + w1.y * x.y + w1.z * x.z + w1.w * x.w;
            acc2[ii] += w2.x * x.x + w2.y * x.y + w2.z * x.z + w2.w * x.w;
        }
    }
    float* out = (tbl < 3) ? (Atab + ((size_t(g) * 3 + tbl) * NCLSP + i0) * MIDW)
                           : (Btab + (size_t(g) * NCLSP + i0) * MIDW);
    for (int ii = 0; ii < nr; ii++) {
        out[size_t(ii) * MIDW + m1] = s * acc1[ii];
        out[size_t(ii) * MIDW + m2] = s * acc2[ii];
    }
}

// 2048 blocks: per-object row sums of graph -> invS = 1/(S+1e-9)
__global__ __launch_bounds__(256) void k_rowsum(const float* graph, float* invS) {
    int o = blockIdx.x;
    const float4* row = (const float4*)(graph + size_t(o) * NREL);
    float s = 0.f;
    for (int i = threadIdx.x; i < NREL / 4; i += blockDim.x) {
        float4 v = row[i];
        s += v.x + v.y + v.z + v.w;
    }
    for (int off = 32; off; off >>= 1) s += __shfl_down(s, off);
    __shared__ float red[4];
    int lane = threadIdx.x & 63, w = threadIdx.x >> 6;
    if (lane == 0) red[w] = s;
    __syncthreads();
    if (threadIdx.x == 0) {
        float t = red[0] + red[1] + red[2] + red[3];
        invS[o] = 1.0f / (t + 1e-9f);
    }
}

// grid (151, 8): Gt[i][r] = sum_{o in class i} graph[o,r] * invS[o]
__global__ __launch_bounds__(256) void k_gbuild(const float* graph, const float* invS,
                                                const int* start, const int* order, float* Gt) {
    int i = blockIdx.x;
    int r0 = blockIdx.y * 4096;
    float4 acc[4];
#pragma unroll
    for (int j = 0; j < 4; j++) acc[j] = make_float4(0.f, 0.f, 0.f, 0.f);
    int s = start[i], e = start[i + 1];
    for (int k = s; k < e; k++) {
        int o = order[k];
        float w = invS[o];
        const float4* row = (const float4*)(graph + size_t(o) * NREL + r0);
#pragma unroll
        for (int j = 0; j < 4; j++) {
            float4 v = row[threadIdx.x + j * 256];
            acc[j].x += w * v.x; acc[j].y += w * v.y; acc[j].z += w * v.z; acc[j].w += w * v.w;
        }
    }
    float4* outp = (float4*)(Gt + size_t(i) * NREL + r0);
#pragma unroll
    for (int j = 0; j < 4; j++) outp[threadIdx.x + j * 256] = acc[j];
}

// grid (8 m-tiles, RS r-chunks): Mpart[rc][g][i][m] = sum_{r in chunk} Gt[i][r] * v_g[r][m]
// v_g[r][m] = relu(Ah_g[h_r][m] + At_g[t_r][m] + Ap_g[p_r][m] + bv_g[m]) computed on the fly.
__global__ __launch_bounds__(256) void k_M(const float* __restrict__ Gt,
                                           const int* __restrict__ relations,
                                           const float* __restrict__ Atab,
                                           const float* __restrict__ lin_v_b,
                                           float* __restrict__ Mpart, int RS) {
    const int mt = blockIdx.x;
    const int rc = blockIdx.y;
    const int rlen = NREL / RS;
    const int r0 = rc * rlen;
    const int tm = threadIdx.x & 63;
    const int tg = threadIdx.x >> 6;          // 0..3 (wave id)
    const int m = mt * 64 + tm;
    const int i0 = tg * 38;                   // 4*38 = 152 padded classes

    const float* Ah0 = Atab + size_t(0) * NCLSP * MIDW;
    const float* At0 = Atab + size_t(1) * NCLSP * MIDW;
    const float* Ap0 = Atab + size_t(2) * NCLSP * MIDW;
    const float* Ah1 = Atab + size_t(3) * NCLSP * MIDW;
    const float* At1 = Atab + size_t(4) * NCLSP * MIDW;
    const float* Ap1 = Atab + size_t(5) * NCLSP * MIDW;
    const float bv0 = lin_v_b[m];
    const float bv1 = lin_v_b[MIDW + m];

    float acc0[38], acc1[38];
#pragma unroll
    for (int j = 0; j < 38; j++) { acc0[j] = 0.f; acc1[j] = 0.f; }

    __shared__ float vbuf[NG][16][64];

    for (int cb = 0; cb < rlen; cb += 16) {
        const int rbase = r0 + cb;
        // ---- cooperative v-tile: 16 rows x 64 m x 2 glimpses ----
#pragma unroll
        for (int k = 0; k < 4; k++) {
            int rr = tg * 4 + k;
            int r = rbase + rr;
            int hh = relations[3 * r + 0];
            int tt = relations[3 * r + 1];
            int pp = relations[3 * r + 2];
            float x0 = Ah0[hh * MIDW + m] + At0[tt * MIDW + m] + Ap0[pp * MIDW + m] + bv0;
            float x1 = Ah1[hh * MIDW + m] + At1[tt * MIDW + m] + Ap1[pp * MIDW + m] + bv1;
            vbuf[0][rr][tm] = fmaxf(x0, 0.f);
            vbuf[1][rr][tm] = fmaxf(x1, 0.f);
        }
        __syncthreads();
        // ---- accumulate: per 4-row group, wave-uniform G loads broadcast across lanes ----
        const float* gbase = Gt + size_t(i0) * NREL + rbase;
#pragma unroll
        for (int rr4 = 0; rr4 < 4; rr4++) {
            float v00 = vbuf[0][rr4 * 4 + 0][tm], v01 = vbuf[0][rr4 * 4 + 1][tm];
            float v02 = vbuf[0][rr4 * 4 + 2][tm], v03 = vbuf[0][rr4 * 4 + 3][tm];
            float v10 = vbuf[1][rr4 * 4 + 0][tm], v11 = vbuf[1][rr4 * 4 + 1][tm];
            float v12 = vbuf[1][rr4 * 4 + 2][tm], v13 = vbuf[1][rr4 * 4 + 3][tm];
            const float* gp = gbase + rr4 * 4;
#pragma unroll
            for (int j = 0; j < 38; j++) {
                const float4 g4 = *(const float4*)(gp + size_t(j) * NREL);
                acc0[j] = fmaf(g4.x, v00, fmaf(g4.y, v01, fmaf(g4.z, v02, fmaf(g4.w, v03, acc0[j]))));
                acc1[j] = fmaf(g4.x, v10, fmaf(g4.y, v11, fmaf(g4.z, v12, fmaf(g4.w, v13, acc1[j]))));
            }
        }
        __syncthreads();
    }

    float* p0 = Mpart + ((size_t(rc) * NG + 0) * NCLSP + i0) * MIDW + m;
    float* p1 = Mpart + ((size_t(rc) * NG + 1) * NCLSP + i0) * MIDW + m;
#pragma unroll
    for (int j = 0; j < 38; j++) {
        p0[size_t(j) * MIDW] = acc0[j];
        p1[size_t(j) * MIDW] = acc1[j];
    }
}

// 608 blocks: reduce Mpart over r-chunks -> M[2][152][512]
__global__ __launch_bounds__(256) void k_mred(const float* Mpart, float* M, int RS) {
    size_t idx = size_t(blockIdx.x) * 256 + threadIdx.x;   // over 2*152*512
    float s = 0.f;
    const size_t stride = size_t(NG) * NCLSP * MIDW;
    for (int rc = 0; rc < RS; rc++) s += Mpart[size_t(rc) * stride + idx];
    M[idx] = s;
}

// 2 blocks: h_g[m] = sum_{i<151} M[g][i][m] * relu(B_g[i][m] + c[m] + bq_g[m])
__global__ void k_h(const float* M, const float* Btab, const float* cvec,
                    const float* lin_q_b, int g, float* hout) {
    int m = blockIdx.x * 256 + threadIdx.x;
    float c = lin_q_b[g * MIDW + m] + (cvec ? cvec[m] : 0.f);
    const float* Mg = M + size_t(g) * NCLSP * MIDW + m;
    const float* Bg = Btab + size_t(g) * NCLSP * MIDW + m;
    float s = 0.f;
    for (int i = 0; i < NCLS; i++)
        s += Mg[size_t(i) * MIDW] * fmaxf(Bg[size_t(i) * MIDW] + c, 0.f);
    hout[m] = s;
}

// 8x64: ah_g[n] = s_a[g] * (h . lin_a_v[g][n][:]) + ba_g[n]
__global__ void k_ah(const float* h, const float* lin_a_v, const float* lin_a_b,
                     const float* scales, int g, float* ah) {
    int n = blockIdx.x * 64 + threadIdx.x;
    const float4* w = (const float4*)(lin_a_v + (size_t(g) * MIDW + n) * MIDW);
    const float4* hv = (const float4*)h;
    float s = 0.f;
    for (int e = 0; e < 128; e++) {
        float4 a = w[e], b = hv[e];
        s += a.x * b.x + a.y * b.y + a.z * b.z + a.w * b.w;
    }
    ah[n] = scales[4 + g] * s + lin_a_b[g * MIDW + n];
}

// 8x64: c1[m] = s_q[1] * (ah0 . lin_q_v[1][m][:])
__global__ void k_c1(const float* ah0, const float* lin_q_v, const float* scales, float* c1) {
    int m = blockIdx.x * 64 + threadIdx.x;
    const float4* w = (const float4*)(lin_q_v + (size_t(1) * MIDW + m) * EMB);
    const float4* av = (const float4*)ah0;
    float s = 0.f;
    for (int e = 0; e < 128; e++) {
        float4 a = w[e], b = av[e];
        s += a.x * b.x + a.y * b.y + a.z * b.z + a.w * b.w;
    }
    c1[m] = scales[3] * s;
}

// 2 blocks: sg[m] = sum_i cnt[i]*obj_tab[i][m] + NOBJ*(ah0[m]+ah1[m])
__global__ void k_sg(const int* cnt, const float* obj_tab, const float* ah, float* sg) {
    int m = blockIdx.x * 256 + threadIdx.x;
    float s = 0.f;
    for (int i = 0; i < NCLS; i++) s += float(cnt[i]) * obj_tab[size_t(i) * EMB + m];
    sg[m] = s + float(NOBJ) * (ah[m] + ah[MIDW + m]);
}

// 8x64: out1 = relu(fc1_w @ sg + fc1_b)
__global__ void k_fc1(const float* sg, const float* fc1_w, const float* fc1_b, float* o1) {
    int n = blockIdx.x * 64 + threadIdx.x;
    const float4* w = (const float4*)(fc1_w + size_t(n) * MIDW);
    const float4* x = (const float4*)sg;
    float s = 0.f;
    for (int e = 0; e < 128; e++) {
        float4 a = w[e], b = x[e];
        s += a.x * b.x + a.y * b.y + a.z * b.z + a.w * b.w;
    }
    o1[n] = fmaxf(s + fc1_b[n], 0.f);
}

// 16x64: out = relu(fc2_w @ o1 + fc2_b)
__global__ void k_fc2(const float* o1, const float* fc2_w, const float* fc2_b, float* out) {
    int n = blockIdx.x * 64 + threadIdx.x;
    const float4* w = (const float4*)(fc2_w + size_t(n) * MIDW);
    const float4* x = (const float4*)o1;
    float s = 0.f;
    for (int e = 0; e < 128; e++) {
        float4 a = w[e], b = x[e];
        s += a.x * b.x + a.y * b.y + a.z * b.z + a.w * b.w;
    }
    out[n] = fmaxf(s + fc2_b[n], 0.f);
}

// ---------------- launch ----------------
extern "C" void kernel_launch(void* const* d_in, const int* in_sizes, int n_in,
                              void* d_out, int out_size, void* d_ws, size_t ws_size,
                              hipStream_t stream) {
    const int*   entities  = (const int*)d_in[0];
    const int*   relations = (const int*)d_in[1];
    const float* graph     = (const float*)d_in[2];
    const float* obj_tab   = (const float*)d_in[3];
    const float* head_tab  = (const float*)d_in[4];
    const float* tail_tab  = (const float*)d_in[5];
    const float* pred_tab  = (const float*)d_in[6];
    const float* lin_v_v   = (const float*)d_in[7];
    const float* lin_v_g   = (const float*)d_in[8];
    const float* lin_v_b   = (const float*)d_in[9];
    const float* lin_q_v   = (const float*)d_in[10];
    const float* lin_q_g   = (const float*)d_in[11];
    const float* lin_q_b   = (const float*)d_in[12];
    const float* lin_a_v   = (const float*)d_in[13];
    const float* lin_a_g   = (const float*)d_in[14];
    const float* lin_a_b   = (const float*)d_in[15];
    const float* fc1_w     = (const float*)d_in[16];
    const float* fc1_b     = (const float*)d_in[17];
    const float* fc2_w     = (const float*)d_in[18];
    const float* fc2_b     = (const float*)d_in[19];
    float* out = (float*)d_out;

    char* ws = (char*)d_ws;
    float* scales = (float*)(ws + OFF_SCALES);
    int*   cnt    = (int*)(ws + OFF_CNT);
    int*   start  = (int*)(ws + OFF_START);
    int*   order  = (int*)(ws + OFF_ORDER);
    float* invS   = (float*)(ws + OFF_INVS);
    float* Atab   = (float*)(ws + OFF_ATAB);
    float* Btab   = (float*)(ws + OFF_BTAB);
    float* Gt     = (float*)(ws + OFF_GT);
    float* Mfull  = (float*)(ws + OFF_M);
    float* hbuf   = (float*)(ws + OFF_H);
    float* ahbuf  = (float*)(ws + OFF_AH);
    float* c1buf  = (float*)(ws + OFF_C1);
    float* sgbuf  = (float*)(ws + OFF_SG);
    float* o1buf  = (float*)(ws + OFF_O1);
    float* Mpart  = (float*)(ws + OFF_MPART);

    // Largest r-chunk split that fits the workspace (OOB-safe fallback chain).
    int RS = 1;
    for (int cand = 64; cand >= 1; cand >>= 1) {
        if (OFF_MPART + size_t(cand) * MPART_UNIT <= ws_size) { RS = cand; break; }
    }

    k_scales<<<6, 256, 0, stream>>>(lin_v_v, lin_v_g, lin_q_v, lin_q_g, lin_a_v, lin_a_g, scales);
    k_bucket<<<1, 256, 0, stream>>>(entities, cnt, start, order);
    k_tables<<<128, 256, 0, stream>>>(obj_tab, head_tab, tail_tab, pred_tab,
                                      lin_v_v, lin_q_v, scales, Atab, Btab);
    k_rowsum<<<NOBJ, 256, 0, stream>>>(graph, invS);
    k_gbuild<<<dim3(NCLS, 8), 256, 0, stream>>>(graph, invS, start, order, Gt);
    k_M<<<dim3(8, RS), 256, 0, stream>>>(Gt, relations, Atab, lin_v_b, Mpart, RS);
    k_mred<<<(NG * NCLSP * MIDW) / 256, 256, 0, stream>>>(Mpart, Mfull, RS);
    k_h<<<2, 256, 0, stream>>>(Mfull, Btab, nullptr, lin_q_b, 0, hbuf);
    k_ah<<<8, 64, 0, stream>>>(hbuf, lin_a_v, lin_a_b, scales, 0, ahbuf);
    k_c1<<<8, 64, 0, stream>>>(ahbuf, lin_q_v, scales, c1buf);
    k_h<<<2, 256, 0, stream>>>(Mfull, Btab, c1buf, lin_q_b, 1, hbuf + MIDW);
    k_ah<<<8, 64, 0, stream>>>(hbuf + MIDW, lin_a_v, lin_a_b, scales, 1, ahbuf + MIDW);
    k_sg<<<2, 256, 0, stream>>>(cnt, obj_tab, ahbuf, sgbuf);
    k_fc1<<<8, 64, 0, stream>>>(sgbuf, fc1_w, fc1_b, o1buf);
    k_fc2<<<16, 64, 0, stream>>>(o1buf, fc2_w, fc2_b, out);
}